// Round 1
// baseline (491.648 us; speedup 1.0000x reference)
//
#include <hip/hip_runtime.h>
#include <math.h>

#define DIMM 512
#define NB 8
#define QLEN 1024
#define KLEN 4096

typedef __attribute__((ext_vector_type(4))) float floatx4;
typedef __attribute__((ext_vector_type(8))) short short8;     // 8 bf16 (4 VGPRs) MFMA frag
typedef __attribute__((ext_vector_type(4))) unsigned short ushort4v;
typedef __attribute__((ext_vector_type(8))) unsigned short ushort8v;

// ---------- bf16 helpers (bit-level, RNE) ----------
static __device__ __forceinline__ unsigned short f2bf(float f) {
    unsigned u = __builtin_bit_cast(unsigned, f);
    u += 0x7FFFu + ((u >> 16) & 1u);
    return (unsigned short)(u >> 16);
}
static __device__ __forceinline__ float bf2f(unsigned short h) {
    unsigned u = ((unsigned)h) << 16;
    return __builtin_bit_cast(float, u);
}
// register-lean tanh via __expf
static __device__ __forceinline__ float fast_tanh(float x) {
    float e = __expf(-2.0f * fabsf(x));
    float t = (1.0f - e) / (1.0f + e);
    return copysignf(t, x);
}

// ---------- async global->LDS, 16B per lane ----------
static __device__ __forceinline__ void gload16(const unsigned short* g, unsigned short* l) {
    __builtin_amdgcn_global_load_lds(
        (__attribute__((address_space(1))) void*)const_cast<unsigned short*>(g),
        (__attribute__((address_space(3))) void*)l,
        16, 0, 0);
}

// ---------- prep: fp32 [R,512] -> bf16 [R,1024] = [lo | hi] ----------
// [lo|hi] (not [hi|lo]) so that after QK, cols 512:1024 ARE combined[:,512:]=output_hi
// in place -> the former conv_hi(outp) dispatch is deleted.
__global__ __launch_bounds__(256) void split_k(const float* __restrict__ x,
                                               unsigned short* __restrict__ dst) {
    int idx = blockIdx.x * 256 + threadIdx.x;          // one float4 per thread
    float4 v = ((const float4*)x)[idx];
    int r = idx >> 7;                                  // 128 float4 per row (C=512)
    int c = (idx & 127) << 2;
    float f[4] = {v.x, v.y, v.z, v.w};
    ushort4v hi, lo;
#pragma unroll
    for (int e = 0; e < 4; ++e) {
        unsigned short h = f2bf(f[e]);
        hi[e] = h;
        lo[e] = f2bf(f[e] - bf2f(h));
    }
    unsigned short* row = dst + ((size_t)r << 10);     // row stride 1024
    *(ushort4v*)(row + c) = lo;
    *(ushort4v*)(row + 512 + c) = hi;
}

// ---------- prep: fp32 [R,C] -> bf16 at dst[r*ldd + off + c] ----------
__global__ __launch_bounds__(256) void conv_hi(const float* __restrict__ x,
                                               unsigned short* __restrict__ dst,
                                               int c4shift, int ldd, int off) {
    int idx = blockIdx.x * 256 + threadIdx.x;
    float4 v = ((const float4*)x)[idx];
    int r = idx >> c4shift;
    int c = (idx & ((1 << c4shift) - 1)) << 2;
    ushort4v hi;
    hi[0] = f2bf(v.x); hi[1] = f2bf(v.y); hi[2] = f2bf(v.z); hi[3] = f2bf(v.w);
    *(ushort4v*)(dst + (size_t)r * ldd + off + c) = hi;
}

// ---------- fused ctx prep: read ctx ONCE ->
//   hilo [b,4096, hi512|lo512] (QK B-operand) + ctxT [b,512,4096] bf16 hi (PV B) ----------
__global__ __launch_bounds__(256) void prep_ctx(const float* __restrict__ ctx,
                                                unsigned short* __restrict__ hilo,
                                                unsigned short* __restrict__ ctxT) {
    __shared__ unsigned short tile[64][66];            // +2 pad: spread banks
    int b = blockIdx.z;
    int c0 = blockIdx.x * 64;                          // dim index
    int k0 = blockIdx.y * 64;                          // seq index
    const float* src = ctx + ((size_t)b * KLEN + k0) * DIMM + c0;
    unsigned short* hl = hilo + ((size_t)b * KLEN + k0) * 1024 + c0;
    int t = threadIdx.x;
    int rr = t >> 4, cc4 = (t & 15) * 4;
#pragma unroll
    for (int it = 0; it < 4; ++it) {
        int r = rr + it * 16;
        float4 v = *(const float4*)(src + (size_t)r * DIMM + cc4);
        float f[4] = {v.x, v.y, v.z, v.w};
        ushort4v hi, lo;
#pragma unroll
        for (int e = 0; e < 4; ++e) {
            unsigned short h = f2bf(f[e]);
            hi[e] = h;
            lo[e] = f2bf(f[e] - bf2f(h));
            tile[r][cc4 + e] = h;
        }
        *(ushort4v*)(hl + (size_t)r * 1024 + cc4) = hi;
        *(ushort4v*)(hl + (size_t)r * 1024 + 512 + cc4) = lo;
    }
    __syncthreads();
#pragma unroll
    for (int it = 0; it < 2; ++it) {
        int u = t + it * 256;
        int c = u >> 3;                                // 0..63 (dim within tile)
        int kk = (u & 7) * 8;                          // 16B chunk along k
        ushort8v o;
#pragma unroll
        for (int e = 0; e < 8; ++e) o[e] = tile[kk + e][c];
        *(ushort8v*)(ctxT + ((size_t)b * DIMM + c0 + c) * KLEN + k0 + kk) = o;
    }
}

// ---------- softmax over rows of 4096: fp32 in-place + bf16 copy ----------
__global__ __launch_bounds__(256) void softmax_k(float* __restrict__ S,
                                                 unsigned short* __restrict__ Pb) {
    size_t row = blockIdx.x;
    float* p = S + row * KLEN;
    int t = threadIdx.x;
    int lane = t & 63, wv = t >> 6;
    float4 v[4];
    float mx = -3.0e38f;
#pragma unroll
    for (int i = 0; i < 4; ++i) {
        v[i] = *(const float4*)(p + i * 1024 + t * 4);
        mx = fmaxf(mx, fmaxf(fmaxf(v[i].x, v[i].y), fmaxf(v[i].z, v[i].w)));
    }
#pragma unroll
    for (int m = 32; m >= 1; m >>= 1) mx = fmaxf(mx, __shfl_xor(mx, m, 64));
    __shared__ float redm[4], reds[4];
    if (lane == 0) redm[wv] = mx;
    __syncthreads();
    mx = fmaxf(fmaxf(redm[0], redm[1]), fmaxf(redm[2], redm[3]));
    float sum = 0.f;
#pragma unroll
    for (int i = 0; i < 4; ++i) {
        v[i].x = __expf(v[i].x - mx); v[i].y = __expf(v[i].y - mx);
        v[i].z = __expf(v[i].z - mx); v[i].w = __expf(v[i].w - mx);
        sum += v[i].x + v[i].y + v[i].z + v[i].w;
    }
#pragma unroll
    for (int m = 32; m >= 1; m >>= 1) sum += __shfl_xor(sum, m, 64);
    if (lane == 0) reds[wv] = sum;
    __syncthreads();
    float inv = 1.0f / (reds[0] + reds[1] + reds[2] + reds[3]);
    unsigned short* pb = Pb + row * KLEN;
#pragma unroll
    for (int i = 0; i < 4; ++i) {
        float4 w;
        w.x = v[i].x * inv; w.y = v[i].y * inv; w.z = v[i].z * inv; w.w = v[i].w * inv;
        *(float4*)(p + i * 1024 + t * 4) = w;
        ushort4v h;
        h[0] = f2bf(w.x); h[1] = f2bf(w.y); h[2] = f2bf(w.z); h[3] = f2bf(w.w);
        *(ushort4v*)(pb + i * 1024 + t * 4) = h;
    }
}

// ---------- generic C = A * B^T GEMM (both operands K-major bf16), fp32 acc ----------
// BM=128 x BN tile, BK=64, 4 waves 2x2; wave = 4 x (BN/32) frags of 16x16x32 MFMA.
// 16x16x32 read pattern (16 rows x 2 chunks per b128) is the 0-conflict one.
// Occupancy: __launch_bounds__(256,4) + streamed bf frags -> 4 blocks/CU (VGPR=64).
// XOR-swizzled LDS: global chunk (row,c) at physical slot c^(row&7).
// T1 (this round): XCD-aware bijective block swizzle. HW round-robins consecutive
//   flat block ids across the 8 XCD L2s; consecutive WORK ids here share A panels
//   (x-fastest) -> remap so each XCD gets a contiguous work chunk. All grids used
//   are %8==0; identity fallback otherwise. [guide T1: +10% when refetch-limited]
// EPI: 0 = store fp32; 1 = store bf16; 2 = tanh(x + bias[col]) fp32
// REMAP (QK split-bf16, virtual K=1536): A=[Al|Ah], B=[Bh|Bl], 3 panels.
template <int EPI, bool REMAP, int BN>
__global__ __launch_bounds__(256, 4) void gemm_bt(
    const unsigned short* __restrict__ A,
    const unsigned short* __restrict__ Bm,
    float* __restrict__ Cf, unsigned short* __restrict__ Cb,
    const float* __restrict__ bias,
    int Ktiles, long lda, long ldb, long ldc,
    long a_bs, long b_bs, long c_bs) {
    constexpr int NF = BN / 32;                        // B frags per wave (4 or 2)
    __shared__ unsigned short sA[128 * 64];
    __shared__ unsigned short sB[BN * 64];

    // T1 XCD swizzle: recover work coords from hw block id
    int nx = gridDim.x, ny = gridDim.y;
    int nblk = nx * ny * (int)gridDim.z;
    int id = (int)blockIdx.x + nx * ((int)blockIdx.y + ny * (int)blockIdx.z);
    int wid = id;
    if ((nblk & 7) == 0) wid = (id & 7) * (nblk >> 3) + (id >> 3);
    int bx = wid % nx;
    int rem = wid / nx;
    int by = rem % ny;
    int bz = rem / ny;

    const int tid = threadIdx.x;
    const int lane = tid & 63;
    const int wv = tid >> 6;
    const int wm = wv >> 1, wn = wv & 1;
    const int mlane = lane & 15, quad = lane >> 4;
    const unsigned short* Ab = A + (size_t)bz * a_bs + (size_t)by * 128 * lda;
    const unsigned short* Bb = Bm + (size_t)bz * b_bs + (size_t)bx * BN * ldb;
    const int r8 = tid >> 3;          // 0..31: row within staging pass
    const int c8 = (tid & 7) << 3;    // LDS chunk offset (lane-ordered, unswizzled)
    const int cg = ((tid & 7) ^ ((tid >> 3) & 7)) << 3;   // swizzled GLOBAL chunk offset
    unsigned short* la = sA + r8 * 64 + c8;
    unsigned short* lb = sB + r8 * 64 + c8;

    floatx4 acc[4][NF] = {};

    for (int kt = 0; kt < Ktiles; ++kt) {
        long kv = (long)kt * 64;
        long ka = kv, kb = kv;
        if (REMAP) {
            ka = kv < 512 ? kv + 512 : (kv < 1024 ? kv : kv - 1024);
            kb = kv < 1024 ? kv : kv - 1024;
        }
        if (kt) __syncthreads();                       // protect LDS from overwrite
        const unsigned short* ga = Ab + (size_t)r8 * lda + ka + cg;
        const unsigned short* gb = Bb + (size_t)r8 * ldb + kb + cg;
#pragma unroll
        for (int it = 0; it < 4; ++it)
            gload16(ga + (size_t)(it * 32) * lda, la + it * 2048);
#pragma unroll
        for (int it = 0; it < BN / 32; ++it)
            gload16(gb + (size_t)(it * 32) * ldb, lb + it * 2048);
        __syncthreads();                               // drains vmcnt before barrier
#pragma unroll
        for (int s = 0; s < 2; ++s) {
            const int swz = (((s * 4 + quad) ^ (mlane & 7)) << 3);
            short8 af[4];
#pragma unroll
            for (int i = 0; i < 4; ++i)
                af[i] = *(const short8*)(sA + (wm * 64 + i * 16 + mlane) * 64 + swz);
#pragma unroll
            for (int j = 0; j < NF; ++j) {             // stream bf: keeps live regs low
                short8 bfj = *(const short8*)(sB + (wn * (BN / 2) + j * 16 + mlane) * 64 + swz);
#pragma unroll
                for (int i = 0; i < 4; ++i)
                    acc[i][j] = __builtin_amdgcn_mfma_f32_16x16x32_bf16(af[i], bfj, acc[i][j], 0, 0, 0);
            }
        }
    }

    // epilogue: C/D layout col=lane&15, row=quad*4+reg
    size_t crow0 = (size_t)by * 128 + wm * 64 + quad * 4;
    size_t ccol0 = (size_t)bx * BN + wn * (BN / 2) + mlane;
    size_t cbase = (size_t)bz * c_bs;
#pragma unroll
    for (int i = 0; i < 4; ++i) {
#pragma unroll
        for (int j = 0; j < NF; ++j) {
            size_t gr = crow0 + i * 16;
            size_t gc = ccol0 + j * 16;
#pragma unroll
            for (int r = 0; r < 4; ++r) {
                float vv = acc[i][j][r];
                size_t off = cbase + (gr + r) * ldc + gc;
                if (EPI == 0) Cf[off] = vv;
                else if (EPI == 1) Cb[off] = f2bf(vv);
                else Cf[off] = fast_tanh(vv + bias[gc]);
            }
        }
    }
}

extern "C" void kernel_launch(void* const* d_in, const int* in_sizes, int n_in,
                              void* d_out, int out_size, void* d_ws, size_t ws_size,
                              hipStream_t stream) {
    (void)in_sizes; (void)n_in; (void)out_size; (void)ws_size;
    const float* outp = (const float*)d_in[0];   // [8,1024,512]
    const float* ctx  = (const float*)d_in[1];   // [8,4096,512]
    const float* W    = (const float*)d_in[2];   // [512,1024]  (already K-major for C=A*W^T)
    const float* bias = (const float*)d_in[3];   // [512]

    float* out0 = (float*)d_out;                              // [8,1024,512]
    float* attn = out0 + (size_t)NB * QLEN * DIMM;            // [8,1024,4096]

    unsigned char* w = (unsigned char*)d_ws;
    // Region plan (113 MiB peak, time-aliased):
    //   R1 (16 MiB): A2 = [outLo|outHi]          -> later: combined [mix | outHi] (hi in place)
    //   R2 (64 MiB): B2 = [ctxHi|ctxLo]          -> later: attn bf16
    //   R3 (32 MiB): ctxT hi bf16 [b,512,4096]
    //   R4 ( 1 MiB): W bf16
    unsigned short* R1 = (unsigned short*)(w);
    unsigned short* R2 = (unsigned short*)(w + (16ull << 20));
    unsigned short* R3 = (unsigned short*)(w + (80ull << 20));
    unsigned short* R4 = (unsigned short*)(w + (112ull << 20));

    // 1. prep (ctx read once: hilo + transpose fused)
    split_k<<<4096, 256, 0, stream>>>(outp, R1);                     // output -> [lo|hi]
    prep_ctx<<<dim3(8, 64, 8), 256, 0, stream>>>(ctx, R2, R3);       // ctx -> B2 + ctxT
    conv_hi<<<512, 256, 0, stream>>>(W, R4, 8, 1024, 0);             // W -> bf16

    // 2. QK^T split-bf16 (virtual K=1536) -> raw logits in attn region
    gemm_bt<0, true, 128><<<dim3(32, 8, 8), 256, 0, stream>>>(
        R1, R2, attn, nullptr, nullptr,
        24, 1024, 1024, 4096,
        (long)QLEN * 1024, (long)KLEN * 1024, (long)QLEN * KLEN);

    // 3. softmax rows: fp32 in-place + bf16 copy into R2 (B2 is dead)
    softmax_k<<<8192, 256, 0, stream>>>(attn, R2);

    // 4. PV: mix = attn_bf16 * ctxT^T -> combined[:,0:512] (bf16, overwrites dead outLo)
    //    BN 64->128: NF=4 doubles MFMA per staged byte; A-panel re-read 8x -> 4x.
    gemm_bt<1, false, 128><<<dim3(4, 8, 8), 256, 0, stream>>>(
        R2, R3, nullptr, R1, nullptr,
        64, 4096, 4096, 1024,
        (long)QLEN * KLEN, (long)DIMM * KLEN, (long)QLEN * 1024);

    // 5. out = tanh(combined * W^T + b)   (combined = [mix | outHi] already assembled)
    //    BN 64->128 likewise.
    gemm_bt<2, false, 128><<<dim3(4, 64, 1), 256, 0, stream>>>(
        R1, R4, out0, nullptr, bias,
        16, 1024, 1024, 512, 0, 0, 0);
}

// Round 2
// 490.044 us; speedup vs baseline: 1.0033x; 1.0033x over previous
//
#include <hip/hip_runtime.h>
#include <math.h>

#define DIMM 512
#define NB 8
#define QLEN 1024
#define KLEN 4096

typedef __attribute__((ext_vector_type(4))) float floatx4;
typedef __attribute__((ext_vector_type(8))) short short8;     // 8 bf16 (4 VGPRs) MFMA frag
typedef __attribute__((ext_vector_type(4))) unsigned short ushort4v;
typedef __attribute__((ext_vector_type(8))) unsigned short ushort8v;

// ---------- bf16 helpers (bit-level, RNE) ----------
static __device__ __forceinline__ unsigned short f2bf(float f) {
    unsigned u = __builtin_bit_cast(unsigned, f);
    u += 0x7FFFu + ((u >> 16) & 1u);
    return (unsigned short)(u >> 16);
}
static __device__ __forceinline__ float bf2f(unsigned short h) {
    unsigned u = ((unsigned)h) << 16;
    return __builtin_bit_cast(float, u);
}
// register-lean tanh via __expf
static __device__ __forceinline__ float fast_tanh(float x) {
    float e = __expf(-2.0f * fabsf(x));
    float t = (1.0f - e) / (1.0f + e);
    return copysignf(t, x);
}

// ---------- async global->LDS, 16B per lane ----------
static __device__ __forceinline__ void gload16(const unsigned short* g, unsigned short* l) {
    __builtin_amdgcn_global_load_lds(
        (__attribute__((address_space(1))) void*)const_cast<unsigned short*>(g),
        (__attribute__((address_space(3))) void*)l,
        16, 0, 0);
}

// ---------- prep: fp32 [R,512] -> bf16 [R,1024] = [lo | hi] ----------
__global__ __launch_bounds__(256) void split_k(const float* __restrict__ x,
                                               unsigned short* __restrict__ dst) {
    int idx = blockIdx.x * 256 + threadIdx.x;          // one float4 per thread
    float4 v = ((const float4*)x)[idx];
    int r = idx >> 7;                                  // 128 float4 per row (C=512)
    int c = (idx & 127) << 2;
    float f[4] = {v.x, v.y, v.z, v.w};
    ushort4v hi, lo;
#pragma unroll
    for (int e = 0; e < 4; ++e) {
        unsigned short h = f2bf(f[e]);
        hi[e] = h;
        lo[e] = f2bf(f[e] - bf2f(h));
    }
    unsigned short* row = dst + ((size_t)r << 10);     // row stride 1024
    *(ushort4v*)(row + c) = lo;
    *(ushort4v*)(row + 512 + c) = hi;
}

// ---------- prep: fp32 [R,C] -> bf16 at dst[r*ldd + off + c] ----------
__global__ __launch_bounds__(256) void conv_hi(const float* __restrict__ x,
                                               unsigned short* __restrict__ dst,
                                               int c4shift, int ldd, int off) {
    int idx = blockIdx.x * 256 + threadIdx.x;
    float4 v = ((const float4*)x)[idx];
    int r = idx >> c4shift;
    int c = (idx & ((1 << c4shift) - 1)) << 2;
    ushort4v hi;
    hi[0] = f2bf(v.x); hi[1] = f2bf(v.y); hi[2] = f2bf(v.z); hi[3] = f2bf(v.w);
    *(ushort4v*)(dst + (size_t)r * ldd + off + c) = hi;
}

// ---------- fused ctx prep: read ctx ONCE ->
//   hilo [b,4096, hi512|lo512] (QK B-operand) + ctxT [b,512,4096] bf16 hi (PV B) ----------
__global__ __launch_bounds__(256) void prep_ctx(const float* __restrict__ ctx,
                                                unsigned short* __restrict__ hilo,
                                                unsigned short* __restrict__ ctxT) {
    __shared__ unsigned short tile[64][66];            // +2 pad: spread banks
    int b = blockIdx.z;
    int c0 = blockIdx.x * 64;                          // dim index
    int k0 = blockIdx.y * 64;                          // seq index
    const float* src = ctx + ((size_t)b * KLEN + k0) * DIMM + c0;
    unsigned short* hl = hilo + ((size_t)b * KLEN + k0) * 1024 + c0;
    int t = threadIdx.x;
    int rr = t >> 4, cc4 = (t & 15) * 4;
#pragma unroll
    for (int it = 0; it < 4; ++it) {
        int r = rr + it * 16;
        float4 v = *(const float4*)(src + (size_t)r * DIMM + cc4);
        float f[4] = {v.x, v.y, v.z, v.w};
        ushort4v hi, lo;
#pragma unroll
        for (int e = 0; e < 4; ++e) {
            unsigned short h = f2bf(f[e]);
            hi[e] = h;
            lo[e] = f2bf(f[e] - bf2f(h));
            tile[r][cc4 + e] = h;
        }
        *(ushort4v*)(hl + (size_t)r * 1024 + cc4) = hi;
        *(ushort4v*)(hl + (size_t)r * 1024 + 512 + cc4) = lo;
    }
    __syncthreads();
#pragma unroll
    for (int it = 0; it < 2; ++it) {
        int u = t + it * 256;
        int c = u >> 3;                                // 0..63 (dim within tile)
        int kk = (u & 7) * 8;                          // 16B chunk along k
        ushort8v o;
#pragma unroll
        for (int e = 0; e < 8; ++e) o[e] = tile[kk + e][c];
        *(ushort8v*)(ctxT + ((size_t)b * DIMM + c0 + c) * KLEN + k0 + kk) = o;
    }
}

// ---------- softmax over rows of 4096: fp32 in-place + bf16 copy ----------
__global__ __launch_bounds__(256) void softmax_k(float* __restrict__ S,
                                                 unsigned short* __restrict__ Pb) {
    size_t row = blockIdx.x;
    float* p = S + row * KLEN;
    int t = threadIdx.x;
    int lane = t & 63, wv = t >> 6;
    float4 v[4];
    float mx = -3.0e38f;
#pragma unroll
    for (int i = 0; i < 4; ++i) {
        v[i] = *(const float4*)(p + i * 1024 + t * 4);
        mx = fmaxf(mx, fmaxf(fmaxf(v[i].x, v[i].y), fmaxf(v[i].z, v[i].w)));
    }
#pragma unroll
    for (int m = 32; m >= 1; m >>= 1) mx = fmaxf(mx, __shfl_xor(mx, m, 64));
    __shared__ float redm[4], reds[4];
    if (lane == 0) redm[wv] = mx;
    __syncthreads();
    mx = fmaxf(fmaxf(redm[0], redm[1]), fmaxf(redm[2], redm[3]));
    float sum = 0.f;
#pragma unroll
    for (int i = 0; i < 4; ++i) {
        v[i].x = __expf(v[i].x - mx); v[i].y = __expf(v[i].y - mx);
        v[i].z = __expf(v[i].z - mx); v[i].w = __expf(v[i].w - mx);
        sum += v[i].x + v[i].y + v[i].z + v[i].w;
    }
#pragma unroll
    for (int m = 32; m >= 1; m >>= 1) sum += __shfl_xor(sum, m, 64);
    if (lane == 0) reds[wv] = sum;
    __syncthreads();
    float inv = 1.0f / (reds[0] + reds[1] + reds[2] + reds[3]);
    unsigned short* pb = Pb + row * KLEN;
#pragma unroll
    for (int i = 0; i < 4; ++i) {
        float4 w;
        w.x = v[i].x * inv; w.y = v[i].y * inv; w.z = v[i].z * inv; w.w = v[i].w * inv;
        *(float4*)(p + i * 1024 + t * 4) = w;
        ushort4v h;
        h[0] = f2bf(w.x); h[1] = f2bf(w.y); h[2] = f2bf(w.z); h[3] = f2bf(w.w);
        *(ushort4v*)(pb + i * 1024 + t * 4) = h;
    }
}

// ---------- generic C = A * B^T GEMM (both operands K-major bf16), fp32 acc ----------
// BM=128 x BN tile, BK=64, 4 waves 2x2; wave = 4 x (BN/32) frags of 16x16x32 MFMA.
// R2 (this round): T4 counted-vmcnt double-buffered pipeline (catalog "minimum 2-phase"):
//   stage(next tile, buf^1) -> s_waitcnt vmcnt(NLOADS) [retire CURRENT tile's loads,
//   keep next tile's NLOADS in flight ACROSS the barrier] -> raw s_barrier ->
//   ds_read+MFMA -> raw s_barrier [readers done before next iter overwrites buf].
//   Never vmcnt(0) in the main loop. Raw s_barrier (not __syncthreads) avoids the
//   compiler's full vmcnt(0)+lgkmcnt(0) drain that capped the old structure at ~950 TF.
// LDS: QK(BN=128) 64 KB -> 2 blocks/CU; PV/out(BN=64) 48 KB -> 3 blocks/CU.
// T1 XCD swizzle REVERTED: with nx%8==0 the default round-robin already gives perfect
//   per-XCD B-panel locality ((bx+32g)%8 = bx%8); the chunked remap broke it
//   (FETCH 151->233 MB, QK +12 us measured round 1).
// EPI: 0 = store fp32; 1 = store bf16; 2 = tanh(x + bias[col]) fp32
// REMAP (QK split-bf16, virtual K=1536): A=[Al|Ah], B=[Bh|Bl], 3 panels.
template <int EPI, bool REMAP, int BN>
__global__ __launch_bounds__(256, 2) void gemm_bt(
    const unsigned short* __restrict__ A,
    const unsigned short* __restrict__ Bm,
    float* __restrict__ Cf, unsigned short* __restrict__ Cb,
    const float* __restrict__ bias,
    int Ktiles, long lda, long ldb, long ldc,
    long a_bs, long b_bs, long c_bs) {
    constexpr int NF = BN / 32;                        // B frags per wave (4 or 2)
    constexpr int NLOADS = 4 + BN / 32;                // gload_lds instrs per wave per tile
    __shared__ unsigned short sA[2][128 * 64];
    __shared__ unsigned short sB[2][BN * 64];
    const int tid = threadIdx.x;
    const int lane = tid & 63;
    const int wv = tid >> 6;
    const int wm = wv >> 1, wn = wv & 1;
    const int mlane = lane & 15, quad = lane >> 4;
    const unsigned short* Ab = A + (size_t)blockIdx.z * a_bs + (size_t)blockIdx.y * 128 * lda;
    const unsigned short* Bb = Bm + (size_t)blockIdx.z * b_bs + (size_t)blockIdx.x * BN * ldb;
    const int r8 = tid >> 3;          // 0..31: row within staging pass
    const int c8 = (tid & 7) << 3;    // LDS chunk offset (lane-ordered, unswizzled)
    const int cg = ((tid & 7) ^ ((tid >> 3) & 7)) << 3;   // swizzled GLOBAL chunk offset

    floatx4 acc[4][NF] = {};

    // stage K-tile kt into LDS buffer b (issue only; no wait here)
    auto stage = [&](int b, int kt) {
        long kv = (long)kt * 64;
        long ka = kv, kb = kv;
        if (REMAP) {
            ka = kv < 512 ? kv + 512 : (kv < 1024 ? kv : kv - 1024);
            kb = kv < 1024 ? kv : kv - 1024;
        }
        const unsigned short* ga = Ab + (size_t)r8 * lda + ka + cg;
        const unsigned short* gb = Bb + (size_t)r8 * ldb + kb + cg;
        unsigned short* la = sA[b] + r8 * 64 + c8;
        unsigned short* lb = sB[b] + r8 * 64 + c8;
#pragma unroll
        for (int it = 0; it < 4; ++it)
            gload16(ga + (size_t)(it * 32) * lda, la + it * 2048);
#pragma unroll
        for (int it = 0; it < BN / 32; ++it)
            gload16(gb + (size_t)(it * 32) * ldb, lb + it * 2048);
    };

    // prologue: tile 0 fully resident
    stage(0, 0);
    asm volatile("s_waitcnt vmcnt(0)" ::: "memory");
    __builtin_amdgcn_s_barrier();

    int cur = 0;
    for (int kt = 0; kt < Ktiles; ++kt) {
        if (kt + 1 < Ktiles) {
            stage(cur ^ 1, kt + 1);                    // issue next tile; stays in flight
            if constexpr (NLOADS == 8)
                asm volatile("s_waitcnt vmcnt(8)" ::: "memory");
            else
                asm volatile("s_waitcnt vmcnt(6)" ::: "memory");
        } else {
            asm volatile("s_waitcnt vmcnt(0)" ::: "memory");
        }
        __builtin_amdgcn_s_barrier();                  // tile kt visible to all waves
        const unsigned short* pA = sA[cur];
        const unsigned short* pB = sB[cur];
#pragma unroll
        for (int s = 0; s < 2; ++s) {
            const int swz = (((s * 4 + quad) ^ (mlane & 7)) << 3);
            short8 af[4];
#pragma unroll
            for (int i = 0; i < 4; ++i)
                af[i] = *(const short8*)(pA + (wm * 64 + i * 16 + mlane) * 64 + swz);
#pragma unroll
            for (int j = 0; j < NF; ++j) {             // stream bf: keeps live regs low
                short8 bfj = *(const short8*)(pB + (wn * (BN / 2) + j * 16 + mlane) * 64 + swz);
#pragma unroll
                for (int i = 0; i < 4; ++i)
                    acc[i][j] = __builtin_amdgcn_mfma_f32_16x16x32_bf16(af[i], bfj, acc[i][j], 0, 0, 0);
            }
        }
        __builtin_amdgcn_s_barrier();                  // readers done -> buf reusable next iter
        cur ^= 1;
    }

    // epilogue: C/D layout col=lane&15, row=quad*4+reg
    size_t crow0 = (size_t)blockIdx.y * 128 + wm * 64 + quad * 4;
    size_t ccol0 = (size_t)blockIdx.x * BN + wn * (BN / 2) + mlane;
    size_t cbase = (size_t)blockIdx.z * c_bs;
#pragma unroll
    for (int i = 0; i < 4; ++i) {
#pragma unroll
        for (int j = 0; j < NF; ++j) {
            size_t gr = crow0 + i * 16;
            size_t gc = ccol0 + j * 16;
#pragma unroll
            for (int r = 0; r < 4; ++r) {
                float vv = acc[i][j][r];
                size_t off = cbase + (gr + r) * ldc + gc;
                if (EPI == 0) Cf[off] = vv;
                else if (EPI == 1) Cb[off] = f2bf(vv);
                else Cf[off] = fast_tanh(vv + bias[gc]);
            }
        }
    }
}

extern "C" void kernel_launch(void* const* d_in, const int* in_sizes, int n_in,
                              void* d_out, int out_size, void* d_ws, size_t ws_size,
                              hipStream_t stream) {
    (void)in_sizes; (void)n_in; (void)out_size; (void)ws_size;
    const float* outp = (const float*)d_in[0];   // [8,1024,512]
    const float* ctx  = (const float*)d_in[1];   // [8,4096,512]
    const float* W    = (const float*)d_in[2];   // [512,1024]  (already K-major for C=A*W^T)
    const float* bias = (const float*)d_in[3];   // [512]

    float* out0 = (float*)d_out;                              // [8,1024,512]
    float* attn = out0 + (size_t)NB * QLEN * DIMM;            // [8,1024,4096]

    unsigned char* w = (unsigned char*)d_ws;
    // Region plan (113 MiB peak, time-aliased):
    //   R1 (16 MiB): A2 = [outLo|outHi]          -> later: combined [mix | outHi] (hi in place)
    //   R2 (64 MiB): B2 = [ctxHi|ctxLo]          -> later: attn bf16
    //   R3 (32 MiB): ctxT hi bf16 [b,512,4096]
    //   R4 ( 1 MiB): W bf16
    unsigned short* R1 = (unsigned short*)(w);
    unsigned short* R2 = (unsigned short*)(w + (16ull << 20));
    unsigned short* R3 = (unsigned short*)(w + (80ull << 20));
    unsigned short* R4 = (unsigned short*)(w + (112ull << 20));

    // 1. prep (ctx read once: hilo + transpose fused)
    split_k<<<4096, 256, 0, stream>>>(outp, R1);                     // output -> [lo|hi]
    prep_ctx<<<dim3(8, 64, 8), 256, 0, stream>>>(ctx, R2, R3);       // ctx -> B2 + ctxT
    conv_hi<<<512, 256, 0, stream>>>(W, R4, 8, 1024, 0);             // W -> bf16

    // 2. QK^T split-bf16 (virtual K=1536) -> raw logits in attn region
    gemm_bt<0, true, 128><<<dim3(32, 8, 8), 256, 0, stream>>>(
        R1, R2, attn, nullptr, nullptr,
        24, 1024, 1024, 4096,
        (long)QLEN * 1024, (long)KLEN * 1024, (long)QLEN * KLEN);

    // 3. softmax rows: fp32 in-place + bf16 copy into R2 (B2 is dead)
    softmax_k<<<8192, 256, 0, stream>>>(attn, R2);

    // 4. PV: mix = attn_bf16 * ctxT^T -> combined[:,0:512] (bf16, overwrites dead outLo)
    gemm_bt<1, false, 64><<<dim3(8, 8, 8), 256, 0, stream>>>(
        R2, R3, nullptr, R1, nullptr,
        64, 4096, 4096, 1024,
        (long)QLEN * KLEN, (long)DIMM * KLEN, (long)QLEN * 1024);

    // 5. out = tanh(combined * W^T + b)   (combined = [mix | outHi] already assembled)
    gemm_bt<2, false, 64><<<dim3(8, 64, 1), 256, 0, stream>>>(
        R1, R4, out0, nullptr, bias,
        16, 1024, 1024, 512, 0, 0, 0);
}

// Round 3
// 463.680 us; speedup vs baseline: 1.0603x; 1.0569x over previous
//
#include <hip/hip_runtime.h>
#include <math.h>

#define DIMM 512
#define NB 8
#define QLEN 1024
#define KLEN 4096

typedef __attribute__((ext_vector_type(4))) float floatx4;
typedef __attribute__((ext_vector_type(8))) short short8;     // 8 bf16 (4 VGPRs) MFMA frag
typedef __attribute__((ext_vector_type(4))) unsigned short ushort4v;
typedef __attribute__((ext_vector_type(8))) unsigned short ushort8v;

// ---------- bf16 helpers (bit-level, RNE) ----------
static __device__ __forceinline__ unsigned short f2bf(float f) {
    unsigned u = __builtin_bit_cast(unsigned, f);
    u += 0x7FFFu + ((u >> 16) & 1u);
    return (unsigned short)(u >> 16);
}
static __device__ __forceinline__ float bf2f(unsigned short h) {
    unsigned u = ((unsigned)h) << 16;
    return __builtin_bit_cast(float, u);
}
// register-lean tanh via __expf
static __device__ __forceinline__ float fast_tanh(float x) {
    float e = __expf(-2.0f * fabsf(x));
    float t = (1.0f - e) / (1.0f + e);
    return copysignf(t, x);
}

// ---------- async global->LDS, 16B per lane ----------
static __device__ __forceinline__ void gload16(const unsigned short* g, unsigned short* l) {
    __builtin_amdgcn_global_load_lds(
        (__attribute__((address_space(1))) void*)const_cast<unsigned short*>(g),
        (__attribute__((address_space(3))) void*)l,
        16, 0, 0);
}

// ---------- prep: fp32 [R,512] -> bf16 [R,1024] = [lo | hi] ----------
__global__ __launch_bounds__(256) void split_k(const float* __restrict__ x,
                                               unsigned short* __restrict__ dst) {
    int idx = blockIdx.x * 256 + threadIdx.x;          // one float4 per thread
    float4 v = ((const float4*)x)[idx];
    int r = idx >> 7;                                  // 128 float4 per row (C=512)
    int c = (idx & 127) << 2;
    float f[4] = {v.x, v.y, v.z, v.w};
    ushort4v hi, lo;
#pragma unroll
    for (int e = 0; e < 4; ++e) {
        unsigned short h = f2bf(f[e]);
        hi[e] = h;
        lo[e] = f2bf(f[e] - bf2f(h));
    }
    unsigned short* row = dst + ((size_t)r << 10);     // row stride 1024
    *(ushort4v*)(row + c) = lo;
    *(ushort4v*)(row + 512 + c) = hi;
}

// ---------- prep: fp32 [R,C] -> bf16 at dst[r*ldd + off + c] ----------
__global__ __launch_bounds__(256) void conv_hi(const float* __restrict__ x,
                                               unsigned short* __restrict__ dst,
                                               int c4shift, int ldd, int off) {
    int idx = blockIdx.x * 256 + threadIdx.x;
    float4 v = ((const float4*)x)[idx];
    int r = idx >> c4shift;
    int c = (idx & ((1 << c4shift) - 1)) << 2;
    ushort4v hi;
    hi[0] = f2bf(v.x); hi[1] = f2bf(v.y); hi[2] = f2bf(v.z); hi[3] = f2bf(v.w);
    *(ushort4v*)(dst + (size_t)r * ldd + off + c) = hi;
}

// ---------- fused ctx prep: read ctx ONCE ->
//   hilo [b,4096, hi512|lo512] (QK B-operand) + ctxT [b,512,4096] bf16 hi (PV B) ----------
__global__ __launch_bounds__(256) void prep_ctx(const float* __restrict__ ctx,
                                                unsigned short* __restrict__ hilo,
                                                unsigned short* __restrict__ ctxT) {
    __shared__ unsigned short tile[64][66];            // +2 pad: spread banks
    int b = blockIdx.z;
    int c0 = blockIdx.x * 64;                          // dim index
    int k0 = blockIdx.y * 64;                          // seq index
    const float* src = ctx + ((size_t)b * KLEN + k0) * DIMM + c0;
    unsigned short* hl = hilo + ((size_t)b * KLEN + k0) * 1024 + c0;
    int t = threadIdx.x;
    int rr = t >> 4, cc4 = (t & 15) * 4;
#pragma unroll
    for (int it = 0; it < 4; ++it) {
        int r = rr + it * 16;
        float4 v = *(const float4*)(src + (size_t)r * DIMM + cc4);
        float f[4] = {v.x, v.y, v.z, v.w};
        ushort4v hi, lo;
#pragma unroll
        for (int e = 0; e < 4; ++e) {
            unsigned short h = f2bf(f[e]);
            hi[e] = h;
            lo[e] = f2bf(f[e] - bf2f(h));
            tile[r][cc4 + e] = h;
        }
        *(ushort4v*)(hl + (size_t)r * 1024 + cc4) = hi;
        *(ushort4v*)(hl + (size_t)r * 1024 + 512 + cc4) = lo;
    }
    __syncthreads();
#pragma unroll
    for (int it = 0; it < 2; ++it) {
        int u = t + it * 256;
        int c = u >> 3;                                // 0..63 (dim within tile)
        int kk = (u & 7) * 8;                          // 16B chunk along k
        ushort8v o;
#pragma unroll
        for (int e = 0; e < 8; ++e) o[e] = tile[kk + e][c];
        *(ushort8v*)(ctxT + ((size_t)b * DIMM + c0 + c) * KLEN + k0 + kk) = o;
    }
}

// ---------- softmax over rows of 4096: fp32 in-place + bf16 copy ----------
__global__ __launch_bounds__(256) void softmax_k(float* __restrict__ S,
                                                 unsigned short* __restrict__ Pb) {
    size_t row = blockIdx.x;
    float* p = S + row * KLEN;
    int t = threadIdx.x;
    int lane = t & 63, wv = t >> 6;
    float4 v[4];
    float mx = -3.0e38f;
#pragma unroll
    for (int i = 0; i < 4; ++i) {
        v[i] = *(const float4*)(p + i * 1024 + t * 4);
        mx = fmaxf(mx, fmaxf(fmaxf(v[i].x, v[i].y), fmaxf(v[i].z, v[i].w)));
    }
#pragma unroll
    for (int m = 32; m >= 1; m >>= 1) mx = fmaxf(mx, __shfl_xor(mx, m, 64));
    __shared__ float redm[4], reds[4];
    if (lane == 0) redm[wv] = mx;
    __syncthreads();
    mx = fmaxf(fmaxf(redm[0], redm[1]), fmaxf(redm[2], redm[3]));
    float sum = 0.f;
#pragma unroll
    for (int i = 0; i < 4; ++i) {
        v[i].x = __expf(v[i].x - mx); v[i].y = __expf(v[i].y - mx);
        v[i].z = __expf(v[i].z - mx); v[i].w = __expf(v[i].w - mx);
        sum += v[i].x + v[i].y + v[i].z + v[i].w;
    }
#pragma unroll
    for (int m = 32; m >= 1; m >>= 1) sum += __shfl_xor(sum, m, 64);
    if (lane == 0) reds[wv] = sum;
    __syncthreads();
    float inv = 1.0f / (reds[0] + reds[1] + reds[2] + reds[3]);
    unsigned short* pb = Pb + row * KLEN;
#pragma unroll
    for (int i = 0; i < 4; ++i) {
        float4 w;
        w.x = v[i].x * inv; w.y = v[i].y * inv; w.z = v[i].z * inv; w.w = v[i].w * inv;
        *(float4*)(p + i * 1024 + t * 4) = w;
        ushort4v h;
        h[0] = f2bf(w.x); h[1] = f2bf(w.y); h[2] = f2bf(w.z); h[3] = f2bf(w.w);
        *(ushort4v*)(pb + i * 1024 + t * 4) = h;
    }
}

// ---------- generic C = A * B^T GEMM (both operands K-major bf16), fp32 acc ----------
// BM=128 x BN tile, BK=64, 4 waves 2x2; wave = 4 x (BN/32) frags of 16x16x32 MFMA.
// R3: REVERTED to the round-0 single-buffer structure (known-best: QK 108 us, 955 TF
//   effective = this structure's measured ceiling). Both structure experiments
//   (r1 chunked swizzle on QK, r2 counted-vmcnt dbuf at 2 blk/CU) regressed; the
//   128^2 2-barrier loop lives off 4-blocks/CU wave overlap (m114), not pipelining.
// NEW (SWZ): z-chunked XCD remap, applied ONLY where the default dispatch spreads
//   the A-panel sharers across XCDs:
//   - PV (8,8,8): A-sharers (same y,z; x=0..7) have id%8=x -> 8 XCDs -> ~8x A refetch.
//     wid=(id%8)*(nblk/8)+id/8 gives XCD n = batch n; A- and B-sharers co-resident.
//   - out (8,64,1): same defect, same fix (B=W 1MB fits every L2).
//   - QK: default kept (id%8=bx already co-locates the 64MB B-operand's sharers;
//     r1 measured chunking it = +80MB fetch, +12us).
// EPI: 0 = store fp32; 1 = store bf16; 2 = tanh(x + bias[col]) fp32
// REMAP (QK split-bf16, virtual K=1536): A=[Al|Ah], B=[Bh|Bl], 3 panels.
template <int EPI, bool REMAP, int BN, bool SWZ>
__global__ __launch_bounds__(256, 4) void gemm_bt(
    const unsigned short* __restrict__ A,
    const unsigned short* __restrict__ Bm,
    float* __restrict__ Cf, unsigned short* __restrict__ Cb,
    const float* __restrict__ bias,
    int Ktiles, long lda, long ldb, long ldc,
    long a_bs, long b_bs, long c_bs) {
    constexpr int NF = BN / 32;                        // B frags per wave (4 or 2)
    __shared__ unsigned short sA[128 * 64];
    __shared__ unsigned short sB[BN * 64];

    int bx, by, bz;
    if constexpr (SWZ) {
        // bijective z-chunked remap; launch guarantees nblk % 8 == 0
        int nx = gridDim.x, ny = gridDim.y;
        int nblk = nx * ny * (int)gridDim.z;
        int id = (int)blockIdx.x + nx * ((int)blockIdx.y + ny * (int)blockIdx.z);
        int wid = (id & 7) * (nblk >> 3) + (id >> 3);
        bx = wid % nx;
        int rem = wid / nx;
        by = rem % ny;
        bz = rem / ny;
    } else {
        bx = blockIdx.x; by = blockIdx.y; bz = blockIdx.z;
    }

    const int tid = threadIdx.x;
    const int lane = tid & 63;
    const int wv = tid >> 6;
    const int wm = wv >> 1, wn = wv & 1;
    const int mlane = lane & 15, quad = lane >> 4;
    const unsigned short* Ab = A + (size_t)bz * a_bs + (size_t)by * 128 * lda;
    const unsigned short* Bb = Bm + (size_t)bz * b_bs + (size_t)bx * BN * ldb;
    const int r8 = tid >> 3;          // 0..31: row within staging pass
    const int c8 = (tid & 7) << 3;    // LDS chunk offset (lane-ordered, unswizzled)
    const int cg = ((tid & 7) ^ ((tid >> 3) & 7)) << 3;   // swizzled GLOBAL chunk offset
    unsigned short* la = sA + r8 * 64 + c8;
    unsigned short* lb = sB + r8 * 64 + c8;

    floatx4 acc[4][NF] = {};

    for (int kt = 0; kt < Ktiles; ++kt) {
        long kv = (long)kt * 64;
        long ka = kv, kb = kv;
        if (REMAP) {
            ka = kv < 512 ? kv + 512 : (kv < 1024 ? kv : kv - 1024);
            kb = kv < 1024 ? kv : kv - 1024;
        }
        if (kt) __syncthreads();                       // protect LDS from overwrite
        const unsigned short* ga = Ab + (size_t)r8 * lda + ka + cg;
        const unsigned short* gb = Bb + (size_t)r8 * ldb + kb + cg;
#pragma unroll
        for (int it = 0; it < 4; ++it)
            gload16(ga + (size_t)(it * 32) * lda, la + it * 2048);
#pragma unroll
        for (int it = 0; it < BN / 32; ++it)
            gload16(gb + (size_t)(it * 32) * ldb, lb + it * 2048);
        __syncthreads();                               // drains vmcnt before barrier
#pragma unroll
        for (int s = 0; s < 2; ++s) {
            const int swz = (((s * 4 + quad) ^ (mlane & 7)) << 3);
            short8 af[4];
#pragma unroll
            for (int i = 0; i < 4; ++i)
                af[i] = *(const short8*)(sA + (wm * 64 + i * 16 + mlane) * 64 + swz);
#pragma unroll
            for (int j = 0; j < NF; ++j) {             // stream bf: keeps live regs low
                short8 bfj = *(const short8*)(sB + (wn * (BN / 2) + j * 16 + mlane) * 64 + swz);
#pragma unroll
                for (int i = 0; i < 4; ++i)
                    acc[i][j] = __builtin_amdgcn_mfma_f32_16x16x32_bf16(af[i], bfj, acc[i][j], 0, 0, 0);
            }
        }
    }

    // epilogue: C/D layout col=lane&15, row=quad*4+reg
    size_t crow0 = (size_t)by * 128 + wm * 64 + quad * 4;
    size_t ccol0 = (size_t)bx * BN + wn * (BN / 2) + mlane;
    size_t cbase = (size_t)bz * c_bs;
#pragma unroll
    for (int i = 0; i < 4; ++i) {
#pragma unroll
        for (int j = 0; j < NF; ++j) {
            size_t gr = crow0 + i * 16;
            size_t gc = ccol0 + j * 16;
#pragma unroll
            for (int r = 0; r < 4; ++r) {
                float vv = acc[i][j][r];
                size_t off = cbase + (gr + r) * ldc + gc;
                if (EPI == 0) Cf[off] = vv;
                else if (EPI == 1) Cb[off] = f2bf(vv);
                else Cf[off] = fast_tanh(vv + bias[gc]);
            }
        }
    }
}

extern "C" void kernel_launch(void* const* d_in, const int* in_sizes, int n_in,
                              void* d_out, int out_size, void* d_ws, size_t ws_size,
                              hipStream_t stream) {
    (void)in_sizes; (void)n_in; (void)out_size; (void)ws_size;
    const float* outp = (const float*)d_in[0];   // [8,1024,512]
    const float* ctx  = (const float*)d_in[1];   // [8,4096,512]
    const float* W    = (const float*)d_in[2];   // [512,1024]  (already K-major for C=A*W^T)
    const float* bias = (const float*)d_in[3];   // [512]

    float* out0 = (float*)d_out;                              // [8,1024,512]
    float* attn = out0 + (size_t)NB * QLEN * DIMM;            // [8,1024,4096]

    unsigned char* w = (unsigned char*)d_ws;
    // Region plan (113 MiB peak, time-aliased):
    //   R1 (16 MiB): A2 = [outLo|outHi]          -> later: combined [mix | outHi] (hi in place)
    //   R2 (64 MiB): B2 = [ctxHi|ctxLo]          -> later: attn bf16
    //   R3 (32 MiB): ctxT hi bf16 [b,512,4096]
    //   R4 ( 1 MiB): W bf16
    unsigned short* R1 = (unsigned short*)(w);
    unsigned short* R2 = (unsigned short*)(w + (16ull << 20));
    unsigned short* R3 = (unsigned short*)(w + (80ull << 20));
    unsigned short* R4 = (unsigned short*)(w + (112ull << 20));

    // 1. prep (ctx read once: hilo + transpose fused)
    split_k<<<4096, 256, 0, stream>>>(outp, R1);                     // output -> [lo|hi]
    prep_ctx<<<dim3(8, 64, 8), 256, 0, stream>>>(ctx, R2, R3);       // ctx -> B2 + ctxT
    conv_hi<<<512, 256, 0, stream>>>(W, R4, 8, 1024, 0);             // W -> bf16

    // 2. QK^T split-bf16 (virtual K=1536) -> raw logits in attn region
    //    default dispatch (SWZ=false): id%8=bx%8 co-locates B-panel sharers.
    gemm_bt<0, true, 128, false><<<dim3(32, 8, 8), 256, 0, stream>>>(
        R1, R2, attn, nullptr, nullptr,
        24, 1024, 1024, 4096,
        (long)QLEN * 1024, (long)KLEN * 1024, (long)QLEN * KLEN);

    // 3. softmax rows: fp32 in-place + bf16 copy into R2 (B2 is dead)
    softmax_k<<<8192, 256, 0, stream>>>(attn, R2);

    // 4. PV: mix = attn_bf16 * ctxT^T -> combined[:,0:512] (bf16, overwrites dead outLo)
    //    SWZ=true: batch-per-XCD; A-panel (1MB) sharers co-resident -> ~8x less A refetch.
    gemm_bt<1, false, 64, true><<<dim3(8, 8, 8), 256, 0, stream>>>(
        R2, R3, nullptr, R1, nullptr,
        64, 4096, 4096, 1024,
        (long)QLEN * KLEN, (long)DIMM * KLEN, (long)QLEN * 1024);

    // 5. out = tanh(combined * W^T + b)   (combined = [mix | outHi] already assembled)
    //    SWZ=true: y-chunk per XCD co-locates A-panel sharers; W 1MB fits every L2.
    gemm_bt<2, false, 64, true><<<dim3(8, 64, 1), 256, 0, stream>>>(
        R1, R4, out0, nullptr, bias,
        16, 1024, 1024, 512, 0, 0, 0);
}

// Round 4
// 459.497 us; speedup vs baseline: 1.0700x; 1.0091x over previous
//
#include <hip/hip_runtime.h>
#include <math.h>

#define DIMM 512
#define NB 8
#define QLEN 1024
#define KLEN 4096

typedef __attribute__((ext_vector_type(4))) float floatx4;
typedef __attribute__((ext_vector_type(8))) short short8;     // 8 bf16 (4 VGPRs) MFMA frag
typedef __attribute__((ext_vector_type(4))) unsigned short ushort4v;
typedef __attribute__((ext_vector_type(8))) unsigned short ushort8v;

// ---------- bf16 helpers (bit-level, RNE) ----------
static __device__ __forceinline__ unsigned short f2bf(float f) {
    unsigned u = __builtin_bit_cast(unsigned, f);
    u += 0x7FFFu + ((u >> 16) & 1u);
    return (unsigned short)(u >> 16);
}
static __device__ __forceinline__ float bf2f(unsigned short h) {
    unsigned u = ((unsigned)h) << 16;
    return __builtin_bit_cast(float, u);
}
// register-lean tanh via __expf
static __device__ __forceinline__ float fast_tanh(float x) {
    float e = __expf(-2.0f * fabsf(x));
    float t = (1.0f - e) / (1.0f + e);
    return copysignf(t, x);
}

// ---------- async global->LDS, 16B per lane ----------
static __device__ __forceinline__ void gload16(const unsigned short* g, unsigned short* l) {
    __builtin_amdgcn_global_load_lds(
        (__attribute__((address_space(1))) void*)const_cast<unsigned short*>(g),
        (__attribute__((address_space(3))) void*)l,
        16, 0, 0);
}

// ---------- prep: fp32 [R,512] -> bf16 [R,1024] = [lo | hi] ----------
__global__ __launch_bounds__(256) void split_k(const float* __restrict__ x,
                                               unsigned short* __restrict__ dst) {
    int idx = blockIdx.x * 256 + threadIdx.x;          // one float4 per thread
    float4 v = ((const float4*)x)[idx];
    int r = idx >> 7;                                  // 128 float4 per row (C=512)
    int c = (idx & 127) << 2;
    float f[4] = {v.x, v.y, v.z, v.w};
    ushort4v hi, lo;
#pragma unroll
    for (int e = 0; e < 4; ++e) {
        unsigned short h = f2bf(f[e]);
        hi[e] = h;
        lo[e] = f2bf(f[e] - bf2f(h));
    }
    unsigned short* row = dst + ((size_t)r << 10);     // row stride 1024
    *(ushort4v*)(row + c) = lo;
    *(ushort4v*)(row + 512 + c) = hi;
}

// ---------- prep: fp32 [R,C] -> bf16 at dst[r*ldd + off + c] ----------
__global__ __launch_bounds__(256) void conv_hi(const float* __restrict__ x,
                                               unsigned short* __restrict__ dst,
                                               int c4shift, int ldd, int off) {
    int idx = blockIdx.x * 256 + threadIdx.x;
    float4 v = ((const float4*)x)[idx];
    int r = idx >> c4shift;
    int c = (idx & ((1 << c4shift) - 1)) << 2;
    ushort4v hi;
    hi[0] = f2bf(v.x); hi[1] = f2bf(v.y); hi[2] = f2bf(v.z); hi[3] = f2bf(v.w);
    *(ushort4v*)(dst + (size_t)r * ldd + off + c) = hi;
}

// ---------- fused ctx prep: read ctx ONCE ->
//   hilo [b,4096, hi512|lo512] (QK B-operand) + ctxT [b,512,4096] bf16 hi (PV B) ----------
__global__ __launch_bounds__(256) void prep_ctx(const float* __restrict__ ctx,
                                                unsigned short* __restrict__ hilo,
                                                unsigned short* __restrict__ ctxT) {
    __shared__ unsigned short tile[64][66];            // +2 pad: spread banks
    int b = blockIdx.z;
    int c0 = blockIdx.x * 64;                          // dim index
    int k0 = blockIdx.y * 64;                          // seq index
    const float* src = ctx + ((size_t)b * KLEN + k0) * DIMM + c0;
    unsigned short* hl = hilo + ((size_t)b * KLEN + k0) * 1024 + c0;
    int t = threadIdx.x;
    int rr = t >> 4, cc4 = (t & 15) * 4;
#pragma unroll
    for (int it = 0; it < 4; ++it) {
        int r = rr + it * 16;
        float4 v = *(const float4*)(src + (size_t)r * DIMM + cc4);
        float f[4] = {v.x, v.y, v.z, v.w};
        ushort4v hi, lo;
#pragma unroll
        for (int e = 0; e < 4; ++e) {
            unsigned short h = f2bf(f[e]);
            hi[e] = h;
            lo[e] = f2bf(f[e] - bf2f(h));
            tile[r][cc4 + e] = h;
        }
        *(ushort4v*)(hl + (size_t)r * 1024 + cc4) = hi;
        *(ushort4v*)(hl + (size_t)r * 1024 + 512 + cc4) = lo;
    }
    __syncthreads();
#pragma unroll
    for (int it = 0; it < 2; ++it) {
        int u = t + it * 256;
        int c = u >> 3;                                // 0..63 (dim within tile)
        int kk = (u & 7) * 8;                          // 16B chunk along k
        ushort8v o;
#pragma unroll
        for (int e = 0; e < 8; ++e) o[e] = tile[kk + e][c];
        *(ushort8v*)(ctxT + ((size_t)b * DIMM + c0 + c) * KLEN + k0 + kk) = o;
    }
}

// ---------- softmax over rows of 4096: fp32 in-place + bf16 copy ----------
__global__ __launch_bounds__(256) void softmax_k(float* __restrict__ S,
                                                 unsigned short* __restrict__ Pb) {
    size_t row = blockIdx.x;
    float* p = S + row * KLEN;
    int t = threadIdx.x;
    int lane = t & 63, wv = t >> 6;
    float4 v[4];
    float mx = -3.0e38f;
#pragma unroll
    for (int i = 0; i < 4; ++i) {
        v[i] = *(const float4*)(p + i * 1024 + t * 4);
        mx = fmaxf(mx, fmaxf(fmaxf(v[i].x, v[i].y), fmaxf(v[i].z, v[i].w)));
    }
#pragma unroll
    for (int m = 32; m >= 1; m >>= 1) mx = fmaxf(mx, __shfl_xor(mx, m, 64));
    __shared__ float redm[4], reds[4];
    if (lane == 0) redm[wv] = mx;
    __syncthreads();
    mx = fmaxf(fmaxf(redm[0], redm[1]), fmaxf(redm[2], redm[3]));
    float sum = 0.f;
#pragma unroll
    for (int i = 0; i < 4; ++i) {
        v[i].x = __expf(v[i].x - mx); v[i].y = __expf(v[i].y - mx);
        v[i].z = __expf(v[i].z - mx); v[i].w = __expf(v[i].w - mx);
        sum += v[i].x + v[i].y + v[i].z + v[i].w;
    }
#pragma unroll
    for (int m = 32; m >= 1; m >>= 1) sum += __shfl_xor(sum, m, 64);
    if (lane == 0) reds[wv] = sum;
    __syncthreads();
    float inv = 1.0f / (reds[0] + reds[1] + reds[2] + reds[3]);
    unsigned short* pb = Pb + row * KLEN;
#pragma unroll
    for (int i = 0; i < 4; ++i) {
        float4 w;
        w.x = v[i].x * inv; w.y = v[i].y * inv; w.z = v[i].z * inv; w.w = v[i].w * inv;
        *(float4*)(p + i * 1024 + t * 4) = w;
        ushort4v h;
        h[0] = f2bf(w.x); h[1] = f2bf(w.y); h[2] = f2bf(w.z); h[3] = f2bf(w.w);
        *(ushort4v*)(pb + i * 1024 + t * 4) = h;
    }
}

// ================= QK^T: 256x256 8-phase counted-vmcnt kernel =================
// BM=BN=256, BK=64, 512 thr = 8 waves (2M x 4N), wave out 128x64, acc[8][4].
// LDS 128 KB: sA/sB[2 dbuf][2 half][128x64 bf16]; 1 block/CU, 8 waves.
// Virtual K=1536 (REMAP panels AhBh / AhBl / AlBh) -> 24 K-tiles, 12 iters x 2.
// Per iter: tiles u=2i (buf0), v=2i+1 (buf1), 8 phases, each phase:
//   [ds-reads] [1 half-tile stage issue] barrier; lgkmcnt(0); sched_barrier;
//   setprio(1); 16 MFMA; setprio(0); [vmcnt(4) at P3/P7]; barrier; sched_barrier.
// Stage map:  P0:b0(v) P1:b1(v) P2:a0(u+2) P3:a1(u+2) P4:b0(u+2) P5:b1(u+2)
//             P6:a0(v+2) P7:a1(v+2)   (slot's last ds-read is >=1 phase earlier;
//             phase-closing barrier after all waves' lgkmcnt(0) makes reads done
//             block-wide before the next phase's stage overwrites the slot).
// vmcnt(4) before P3.bar2: retires a(v)@P6/P7[i-1] + b(v)@P0/P1 -> P4 reads safe;
//          leaves a(u+2)@P2/P3 in flight (4 loads).
// vmcnt(4) before P7.bar2: retires a(u+2),b(u+2) -> next P0 reads safe;
//          leaves a(v+2)@P6/P7 in flight. Never vmcnt(0) except tail iter.
// vmcnt placed BEFORE the barrier so retirement is ordered block-wide (vmcnt is
// per-wave; barrier publishes it). Frag layout + XOR chunk swizzle identical to
// the verified 128^2 kernel; accumulation order per output element unchanged.
__global__ __launch_bounds__(512, 2) void qk_8ph(
    const unsigned short* __restrict__ Aq,     // [b,1024,1024] = [outLo|outHi]
    const unsigned short* __restrict__ Bc,     // [b,4096,1024] = [ctxHi|ctxLo]
    float* __restrict__ Cf) {                  // [b,1024,4096] logits
    __shared__ unsigned short sA[2][2][8192];
    __shared__ unsigned short sB[2][2][8192];
    const int tid = threadIdx.x;
    const int lane = tid & 63;
    const int wv = tid >> 6;           // 0..7
    const int wm = wv >> 2;            // 0..1  (row half)
    const int wn = wv & 3;             // 0..3  (64-col group)
    const int wb = wn >> 1;            // B half
    const int mlane = lane & 15, quad = lane >> 4;
    const unsigned short* Ab = Aq + (size_t)blockIdx.z * (QLEN * 1024) + (size_t)blockIdx.y * 256 * 1024;
    const unsigned short* Bb = Bc + (size_t)blockIdx.z * ((size_t)KLEN * 1024) + (size_t)blockIdx.x * 256 * 1024;
    const int cg = ((tid & 7) ^ ((tid >> 3) & 7)) << 3;   // swizzled GLOBAL chunk
    const int srow = tid >> 3;                            // 0..63 staging row

    auto kaOf = [](int t) -> long { long kv = t * 64L; return kv < 512 ? kv + 512 : (kv < 1024 ? kv : kv - 1024); };
    auto kbOf = [](int t) -> long { long kv = t * 64L; return kv < 1024 ? kv : kv - 1024; };
    auto stage = [&](const unsigned short* gbase, unsigned short* lbase, long kofs) {
        const unsigned short* g = gbase + (size_t)srow * 1024 + kofs + cg;
        gload16(g, lbase);                                // rows 0..63 of half
        gload16(g + (size_t)64 * 1024, lbase + 4096);     // rows 64..127
    };
    auto stA = [&](int q, int h, int t) { stage(Ab + (size_t)h * 128 * 1024, &sA[q][h][0] + tid * 8, kaOf(t)); };
    auto stB = [&](int q, int h, int t) { stage(Bb + (size_t)h * 128 * 1024, &sB[q][h][0] + tid * 8, kbOf(t)); };

    const unsigned short* const pA[2] = {&sA[0][wm][0], &sA[1][wm][0]};
    const unsigned short* const pB[2] = {&sB[0][wb][0] + (wn & 1) * 4096,
                                         &sB[1][wb][0] + (wn & 1) * 4096};
    auto rdA = [&](int q, int m, int s) -> short8 {
        return *(const short8*)(pA[q] + (m * 16 + mlane) * 64 + (((s * 4 + quad) ^ (mlane & 7)) << 3));
    };
    auto rdB = [&](int q, int n, int s) -> short8 {
        return *(const short8*)(pB[q] + (n * 16 + mlane) * 64 + (((s * 4 + quad) ^ (mlane & 7)) << 3));
    };

#define QK_BAR1() __builtin_amdgcn_s_barrier();                          \
    asm volatile("s_waitcnt lgkmcnt(0)" ::: "memory");                   \
    __builtin_amdgcn_sched_barrier(0);                                   \
    __builtin_amdgcn_s_setprio(1)
#define QK_BAR2() __builtin_amdgcn_s_setprio(0);                         \
    __builtin_amdgcn_s_barrier();                                        \
    __builtin_amdgcn_sched_barrier(0)

    floatx4 acc[8][4] = {};

    // prologue: a(0), b(0), a(1) staged; b(1) is staged by P0/P1 of iter 0.
    stA(0, 0, 0); stA(0, 1, 0); stB(0, 0, 0); stB(0, 1, 0);
    stA(1, 0, 1); stA(1, 1, 1);
    asm volatile("s_waitcnt vmcnt(4)" ::: "memory");      // retire a(0),b(0); a(1) in flight
    __builtin_amdgcn_s_barrier();
    __builtin_amdgcn_sched_barrier(0);

    for (int i = 0; i < 12; ++i) {
        const int u = 2 * i, v = u + 1;
        const bool sg = (i < 11);                          // tiles u+2, v+2 exist
        short8 afL[8], afH[8], bfA[4], bfB[4];
        // ---- P0: tile u, m0-3 x n0-1 ----
#pragma unroll
        for (int m = 0; m < 4; ++m) { afL[m * 2] = rdA(0, m, 0); afL[m * 2 + 1] = rdA(0, m, 1); }
#pragma unroll
        for (int n = 0; n < 2; ++n) { bfA[n * 2] = rdB(0, n, 0); bfA[n * 2 + 1] = rdB(0, n, 1); }
        stB(1, 0, v);
        QK_BAR1();
#pragma unroll
        for (int m = 0; m < 4; ++m)
#pragma unroll
            for (int n = 0; n < 2; ++n)
#pragma unroll
                for (int s = 0; s < 2; ++s)
                    acc[m][n] = __builtin_amdgcn_mfma_f32_16x16x32_bf16(afL[m * 2 + s], bfA[n * 2 + s], acc[m][n], 0, 0, 0);
        QK_BAR2();
        // ---- P1: tile u, m4-7 x n0-1 ----
#pragma unroll
        for (int m = 0; m < 4; ++m) { afH[m * 2] = rdA(0, m + 4, 0); afH[m * 2 + 1] = rdA(0, m + 4, 1); }
        stB(1, 1, v);
        QK_BAR1();
#pragma unroll
        for (int m = 0; m < 4; ++m)
#pragma unroll
            for (int n = 0; n < 2; ++n)
#pragma unroll
                for (int s = 0; s < 2; ++s)
                    acc[m + 4][n] = __builtin_amdgcn_mfma_f32_16x16x32_bf16(afH[m * 2 + s], bfA[n * 2 + s], acc[m + 4][n], 0, 0, 0);
        QK_BAR2();
        // ---- P2: tile u, m0-3 x n2-3 ----
#pragma unroll
        for (int n = 0; n < 2; ++n) { bfB[n * 2] = rdB(0, n + 2, 0); bfB[n * 2 + 1] = rdB(0, n + 2, 1); }
        if (sg) stA(0, 0, u + 2);
        QK_BAR1();
#pragma unroll
        for (int m = 0; m < 4; ++m)
#pragma unroll
            for (int n = 0; n < 2; ++n)
#pragma unroll
                for (int s = 0; s < 2; ++s)
                    acc[m][n + 2] = __builtin_amdgcn_mfma_f32_16x16x32_bf16(afL[m * 2 + s], bfB[n * 2 + s], acc[m][n + 2], 0, 0, 0);
        QK_BAR2();
        // ---- P3: tile u, m4-7 x n2-3; counted vmcnt ----
        if (sg) stA(0, 1, u + 2);
        QK_BAR1();
#pragma unroll
        for (int m = 0; m < 4; ++m)
#pragma unroll
            for (int n = 0; n < 2; ++n)
#pragma unroll
                for (int s = 0; s < 2; ++s)
                    acc[m + 4][n + 2] = __builtin_amdgcn_mfma_f32_16x16x32_bf16(afH[m * 2 + s], bfB[n * 2 + s], acc[m + 4][n + 2], 0, 0, 0);
        __builtin_amdgcn_s_setprio(0);
        if (sg) { asm volatile("s_waitcnt vmcnt(4)" ::: "memory"); }
        else    { asm volatile("s_waitcnt vmcnt(0)" ::: "memory"); }
        __builtin_amdgcn_s_barrier();
        __builtin_amdgcn_sched_barrier(0);
        // ---- P4: tile v, m0-3 x n0-1 ----
#pragma unroll
        for (int m = 0; m < 4; ++m) { afL[m * 2] = rdA(1, m, 0); afL[m * 2 + 1] = rdA(1, m, 1); }
#pragma unroll
        for (int n = 0; n < 2; ++n) { bfA[n * 2] = rdB(1, n, 0); bfA[n * 2 + 1] = rdB(1, n, 1); }
        if (sg) stB(0, 0, u + 2);
        QK_BAR1();
#pragma unroll
        for (int m = 0; m < 4; ++m)
#pragma unroll
            for (int n = 0; n < 2; ++n)
#pragma unroll
                for (int s = 0; s < 2; ++s)
                    acc[m][n] = __builtin_amdgcn_mfma_f32_16x16x32_bf16(afL[m * 2 + s], bfA[n * 2 + s], acc[m][n], 0, 0, 0);
        QK_BAR2();
        // ---- P5: tile v, m4-7 x n0-1 ----
#pragma unroll
        for (int m = 0; m < 4; ++m) { afH[m * 2] = rdA(1, m + 4, 0); afH[m * 2 + 1] = rdA(1, m + 4, 1); }
        if (sg) stB(0, 1, u + 2);
        QK_BAR1();
#pragma unroll
        for (int m = 0; m < 4; ++m)
#pragma unroll
            for (int n = 0; n < 2; ++n)
#pragma unroll
                for (int s = 0; s < 2; ++s)
                    acc[m + 4][n] = __builtin_amdgcn_mfma_f32_16x16x32_bf16(afH[m * 2 + s], bfA[n * 2 + s], acc[m + 4][n], 0, 0, 0);
        QK_BAR2();
        // ---- P6: tile v, m0-3 x n2-3 ----
#pragma unroll
        for (int n = 0; n < 2; ++n) { bfB[n * 2] = rdB(1, n + 2, 0); bfB[n * 2 + 1] = rdB(1, n + 2, 1); }
        if (sg) stA(1, 0, v + 2);
        QK_BAR1();
#pragma unroll
        for (int m = 0; m < 4; ++m)
#pragma unroll
            for (int n = 0; n < 2; ++n)
#pragma unroll
                for (int s = 0; s < 2; ++s)
                    acc[m][n + 2] = __builtin_amdgcn_mfma_f32_16x16x32_bf16(afL[m * 2 + s], bfB[n * 2 + s], acc[m][n + 2], 0, 0, 0);
        QK_BAR2();
        // ---- P7: tile v, m4-7 x n2-3; counted vmcnt ----
        if (sg) stA(1, 1, v + 2);
        QK_BAR1();
#pragma unroll
        for (int m = 0; m < 4; ++m)
#pragma unroll
            for (int n = 0; n < 2; ++n)
#pragma unroll
                for (int s = 0; s < 2; ++s)
                    acc[m + 4][n + 2] = __builtin_amdgcn_mfma_f32_16x16x32_bf16(afH[m * 2 + s], bfB[n * 2 + s], acc[m + 4][n + 2], 0, 0, 0);
        __builtin_amdgcn_s_setprio(0);
        if (sg) { asm volatile("s_waitcnt vmcnt(4)" ::: "memory"); }
        __builtin_amdgcn_s_barrier();
        __builtin_amdgcn_sched_barrier(0);
    }
#undef QK_BAR1
#undef QK_BAR2

    // epilogue: C/D layout col=lane&15, row=quad*4+reg
    const size_t crow0 = (size_t)blockIdx.y * 256 + wm * 128 + quad * 4;
    const size_t ccol0 = (size_t)blockIdx.x * 256 + wn * 64 + mlane;
    float* Cb = Cf + (size_t)blockIdx.z * ((size_t)QLEN * KLEN);
#pragma unroll
    for (int m = 0; m < 8; ++m)
#pragma unroll
        for (int n = 0; n < 4; ++n)
#pragma unroll
            for (int r = 0; r < 4; ++r)
                Cb[(crow0 + m * 16 + r) * KLEN + ccol0 + n * 16] = acc[m][n][r];
}

// ---------- generic C = A * B^T GEMM (both operands K-major bf16), fp32 acc ----------
// (unchanged r3 structure; used for PV and out-GEMM)
template <int EPI, bool REMAP, int BN, bool SWZ>
__global__ __launch_bounds__(256, 4) void gemm_bt(
    const unsigned short* __restrict__ A,
    const unsigned short* __restrict__ Bm,
    float* __restrict__ Cf, unsigned short* __restrict__ Cb,
    const float* __restrict__ bias,
    int Ktiles, long lda, long ldb, long ldc,
    long a_bs, long b_bs, long c_bs) {
    constexpr int NF = BN / 32;                        // B frags per wave (4 or 2)
    __shared__ unsigned short sA[128 * 64];
    __shared__ unsigned short sB[BN * 64];

    int bx, by, bz;
    if constexpr (SWZ) {
        int nx = gridDim.x, ny = gridDim.y;
        int nblk = nx * ny * (int)gridDim.z;
        int id = (int)blockIdx.x + nx * ((int)blockIdx.y + ny * (int)blockIdx.z);
        int wid = (id & 7) * (nblk >> 3) + (id >> 3);
        bx = wid % nx;
        int rem = wid / nx;
        by = rem % ny;
        bz = rem / ny;
    } else {
        bx = blockIdx.x; by = blockIdx.y; bz = blockIdx.z;
    }

    const int tid = threadIdx.x;
    const int lane = tid & 63;
    const int wv = tid >> 6;
    const int wm = wv >> 1, wn = wv & 1;
    const int mlane = lane & 15, quad = lane >> 4;
    const unsigned short* Ab = A + (size_t)bz * a_bs + (size_t)by * 128 * lda;
    const unsigned short* Bb = Bm + (size_t)bz * b_bs + (size_t)bx * BN * ldb;
    const int r8 = tid >> 3;
    const int c8 = (tid & 7) << 3;
    const int cg = ((tid & 7) ^ ((tid >> 3) & 7)) << 3;
    unsigned short* la = sA + r8 * 64 + c8;
    unsigned short* lb = sB + r8 * 64 + c8;

    floatx4 acc[4][NF] = {};

    for (int kt = 0; kt < Ktiles; ++kt) {
        long kv = (long)kt * 64;
        long ka = kv, kb = kv;
        if (REMAP) {
            ka = kv < 512 ? kv + 512 : (kv < 1024 ? kv : kv - 1024);
            kb = kv < 1024 ? kv : kv - 1024;
        }
        if (kt) __syncthreads();
        const unsigned short* ga = Ab + (size_t)r8 * lda + ka + cg;
        const unsigned short* gb = Bb + (size_t)r8 * ldb + kb + cg;
#pragma unroll
        for (int it = 0; it < 4; ++it)
            gload16(ga + (size_t)(it * 32) * lda, la + it * 2048);
#pragma unroll
        for (int it = 0; it < BN / 32; ++it)
            gload16(gb + (size_t)(it * 32) * ldb, lb + it * 2048);
        __syncthreads();
#pragma unroll
        for (int s = 0; s < 2; ++s) {
            const int swz = (((s * 4 + quad) ^ (mlane & 7)) << 3);
            short8 af[4];
#pragma unroll
            for (int i = 0; i < 4; ++i)
                af[i] = *(const short8*)(sA + (wm * 64 + i * 16 + mlane) * 64 + swz);
#pragma unroll
            for (int j = 0; j < NF; ++j) {
                short8 bfj = *(const short8*)(sB + (wn * (BN / 2) + j * 16 + mlane) * 64 + swz);
#pragma unroll
                for (int i = 0; i < 4; ++i)
                    acc[i][j] = __builtin_amdgcn_mfma_f32_16x16x32_bf16(af[i], bfj, acc[i][j], 0, 0, 0);
            }
        }
    }

    size_t crow0 = (size_t)by * 128 + wm * 64 + quad * 4;
    size_t ccol0 = (size_t)bx * BN + wn * (BN / 2) + mlane;
    size_t cbase = (size_t)bz * c_bs;
#pragma unroll
    for (int i = 0; i < 4; ++i) {
#pragma unroll
        for (int j = 0; j < NF; ++j) {
            size_t gr = crow0 + i * 16;
            size_t gc = ccol0 + j * 16;
#pragma unroll
            for (int r = 0; r < 4; ++r) {
                float vv = acc[i][j][r];
                size_t off = cbase + (gr + r) * ldc + gc;
                if (EPI == 0) Cf[off] = vv;
                else if (EPI == 1) Cb[off] = f2bf(vv);
                else Cf[off] = fast_tanh(vv + bias[gc]);
            }
        }
    }
}

extern "C" void kernel_launch(void* const* d_in, const int* in_sizes, int n_in,
                              void* d_out, int out_size, void* d_ws, size_t ws_size,
                              hipStream_t stream) {
    (void)in_sizes; (void)n_in; (void)out_size; (void)ws_size;
    const float* outp = (const float*)d_in[0];   // [8,1024,512]
    const float* ctx  = (const float*)d_in[1];   // [8,4096,512]
    const float* W    = (const float*)d_in[2];   // [512,1024]  (already K-major for C=A*W^T)
    const float* bias = (const float*)d_in[3];   // [512]

    float* out0 = (float*)d_out;                              // [8,1024,512]
    float* attn = out0 + (size_t)NB * QLEN * DIMM;            // [8,1024,4096]

    unsigned char* w = (unsigned char*)d_ws;
    // Region plan (113 MiB peak, time-aliased):
    //   R1 (16 MiB): A2 = [outLo|outHi]          -> later: combined [mix | outHi]
    //   R2 (64 MiB): B2 = [ctxHi|ctxLo]          -> later: attn bf16
    //   R3 (32 MiB): ctxT hi bf16 [b,512,4096]
    //   R4 ( 1 MiB): W bf16
    unsigned short* R1 = (unsigned short*)(w);
    unsigned short* R2 = (unsigned short*)(w + (16ull << 20));
    unsigned short* R3 = (unsigned short*)(w + (80ull << 20));
    unsigned short* R4 = (unsigned short*)(w + (112ull << 20));

    // 1. prep (ctx read once: hilo + transpose fused)
    split_k<<<4096, 256, 0, stream>>>(outp, R1);                     // output -> [lo|hi]
    prep_ctx<<<dim3(8, 64, 8), 256, 0, stream>>>(ctx, R2, R3);       // ctx -> B2 + ctxT
    conv_hi<<<512, 256, 0, stream>>>(W, R4, 8, 1024, 0);             // W -> bf16

    // 2. QK^T split-bf16 (virtual K=1536) -> raw logits, 256^2 8-phase kernel
    qk_8ph<<<dim3(16, 4, 8), 512, 0, stream>>>(R1, R2, attn);

    // 3. softmax rows: fp32 in-place + bf16 copy into R2 (B2 is dead)
    softmax_k<<<8192, 256, 0, stream>>>(attn, R2);

    // 4. PV: mix = attn_bf16 * ctxT^T -> combined[:,0:512] (bf16, overwrites dead outLo)
    gemm_bt<1, false, 64, true><<<dim3(8, 8, 8), 256, 0, stream>>>(
        R2, R3, nullptr, R1, nullptr,
        64, 4096, 4096, 1024,
        (long)QLEN * KLEN, (long)DIMM * KLEN, (long)QLEN * 1024);

    // 5. out = tanh(combined * W^T + b)   (combined = [mix | outHi] already assembled)
    gemm_bt<2, false, 64, true><<<dim3(8, 64, 1), 256, 0, stream>>>(
        R1, R4, out0, nullptr, bias,
        16, 1024, 1024, 512, 0, 0, 0);
}